// Round 1
// baseline (31260.324 us; speedup 1.0000x reference)
//
#include <hip/hip_runtime.h>
#include <hip/hip_bf16.h>

// Problem: GRU forward. B=128, S=1024, I=256, H=512.
// inputs  d_in[0]: float32 [128][1024][256]
// W_in    d_in[1]: float32 [256][1536]
// W_h     d_in[2]: float32 [512][1536]
// bias    d_in[3]: float32 [3072]  (b_in = bias[0:1536], b_h = bias[1536:3072])
// d_out: float32 hidden_sequence [128][1024][512] followed by h_last [128][512]
// d_ws: x_proj stored as bf16 [128*1024][1536]  (403 MB)

#define B_DIM 128
#define S_DIM 1024
#define I_DIM 256
#define H_DIM 512
#define G_DIM 1536  // 3*H

static __device__ __forceinline__ float bf2f(ushort u) {
    union { unsigned int i; float f; } v;
    v.i = ((unsigned int)u) << 16;
    return v.f;
}

static __device__ __forceinline__ ushort f2bf(float f) {
    union { float f; unsigned int i; } v;
    v.f = f;
    // round-to-nearest-even
    unsigned int lsb = (v.i >> 16) & 1;
    v.i += 0x7fffu + lsb;
    return (ushort)(v.i >> 16);
}

static __device__ __forceinline__ float sigmoidf(float x) {
    return 1.0f / (1.0f + __expf(-x));
}

// ---------------------------------------------------------------------------
// Kernel 1: x_proj[m][g] = inputs[m][:] @ W_in[:][g] + b_in[g], stored bf16.
// M = 131072, K = 256, N = 1536. Tiled fp32 GEMM: 64x64 tile, 4x4 per thread.
// ---------------------------------------------------------------------------
#define BM 64
#define BN 64
#define BK 16

__global__ __launch_bounds__(256) void xproj_gemm(
    const float* __restrict__ A,      // [131072][256]
    const float* __restrict__ W,      // [256][1536]
    const float* __restrict__ bias,   // b_in at offset 0
    ushort* __restrict__ X)           // [131072][1536] bf16
{
    __shared__ float As[BK][BM + 1];
    __shared__ float Bs[BK][BN];

    const int tid = threadIdx.x;
    const int tx = tid & 15;          // 0..15 col group
    const int ty = tid >> 4;          // 0..15 row group
    const long m0 = (long)blockIdx.x * BM;
    const int n0 = blockIdx.y * BN;

    // A tile load mapping: thread loads float4: row = tid/4, kcols = (tid%4)*4
    const int arow = tid >> 2;
    const int akc = (tid & 3) * 4;
    // B tile load mapping: k-row = tid/16, ncols = (tid%16)*4
    const int bkr = tid >> 4;
    const int bnc = (tid & 15) * 4;

    float acc[4][4] = {};

    for (int k0 = 0; k0 < I_DIM; k0 += BK) {
        float4 av = *(const float4*)(A + (m0 + arow) * I_DIM + k0 + akc);
        As[akc + 0][arow] = av.x;
        As[akc + 1][arow] = av.y;
        As[akc + 2][arow] = av.z;
        As[akc + 3][arow] = av.w;
        float4 bv = *(const float4*)(W + (long)(k0 + bkr) * G_DIM + n0 + bnc);
        *(float4*)&Bs[bkr][bnc] = bv;
        __syncthreads();
#pragma unroll
        for (int k = 0; k < BK; ++k) {
            float a0 = As[k][ty * 4 + 0];
            float a1 = As[k][ty * 4 + 1];
            float a2 = As[k][ty * 4 + 2];
            float a3 = As[k][ty * 4 + 3];
            float4 b = *(const float4*)&Bs[k][tx * 4];
            acc[0][0] += a0 * b.x; acc[0][1] += a0 * b.y; acc[0][2] += a0 * b.z; acc[0][3] += a0 * b.w;
            acc[1][0] += a1 * b.x; acc[1][1] += a1 * b.y; acc[1][2] += a1 * b.z; acc[1][3] += a1 * b.w;
            acc[2][0] += a2 * b.x; acc[2][1] += a2 * b.y; acc[2][2] += a2 * b.z; acc[2][3] += a2 * b.w;
            acc[3][0] += a3 * b.x; acc[3][1] += a3 * b.y; acc[3][2] += a3 * b.z; acc[3][3] += a3 * b.w;
        }
        __syncthreads();
    }

    const float b0v = bias[n0 + tx * 4 + 0];
    const float b1v = bias[n0 + tx * 4 + 1];
    const float b2v = bias[n0 + tx * 4 + 2];
    const float b3v = bias[n0 + tx * 4 + 3];
#pragma unroll
    for (int i = 0; i < 4; ++i) {
        const long m = m0 + ty * 4 + i;
        ushort4 o;
        o.x = f2bf(acc[i][0] + b0v);
        o.y = f2bf(acc[i][1] + b1v);
        o.z = f2bf(acc[i][2] + b2v);
        o.w = f2bf(acc[i][3] + b3v);
        *(ushort4*)(X + m * G_DIM + n0 + tx * 4) = o;
    }
}

// ---------------------------------------------------------------------------
// Kernel 2: sequential GRU scan. 64 blocks x 512 threads; each block owns 2
// batch rows (recurrence is independent per batch row -> no inter-block sync).
// h kept in LDS. W_h streamed from L2 each step (round-0 baseline).
// ---------------------------------------------------------------------------
__global__ __launch_bounds__(512) void gru_scan(
    const float* __restrict__ Wh,     // [512][1536]
    const float* __restrict__ bias,   // full bias; b_h at +1536
    const ushort* __restrict__ X,     // x_proj bf16 [128*1024][1536]
    float* __restrict__ out_seq,      // [128][1024][512]
    float* __restrict__ out_last)     // [128][512]
{
    __shared__ float h[2][H_DIM];

    const int c = threadIdx.x;        // 0..511, this thread's hidden column
    const int b0 = blockIdx.x * 2;    // batch rows b0, b0+1

    h[0][c] = 0.0f;
    h[1][c] = 0.0f;
    __syncthreads();

    const float bh_r = bias[G_DIM + c];
    const float bh_z = bias[G_DIM + H_DIM + c];
    const float bh_n = bias[G_DIM + 2 * H_DIM + c];

    const size_t xbase0 = (size_t)b0 * S_DIM * G_DIM;
    const size_t xbase1 = (size_t)(b0 + 1) * S_DIM * G_DIM;
    const size_t obase0 = (size_t)b0 * S_DIM * H_DIM;
    const size_t obase1 = (size_t)(b0 + 1) * S_DIM * H_DIM;

    for (int t = 0; t < S_DIM; ++t) {
        float ar0 = 0.f, az0 = 0.f, an0 = 0.f;
        float ar1 = 0.f, az1 = 0.f, an1 = 0.f;

        const float* w = Wh + c;
#pragma unroll 8
        for (int k = 0; k < H_DIM; ++k) {
            const float h0 = h[0][k];
            const float h1 = h[1][k];
            const float wr = w[0];
            const float wz = w[H_DIM];
            const float wn = w[2 * H_DIM];
            ar0 += h0 * wr; az0 += h0 * wz; an0 += h0 * wn;
            ar1 += h1 * wr; az1 += h1 * wz; an1 += h1 * wn;
            w += G_DIM;
        }

        const ushort* x0 = X + xbase0 + (size_t)t * G_DIM;
        const ushort* x1 = X + xbase1 + (size_t)t * G_DIM;
        const float xr0 = bf2f(x0[c]);
        const float xz0 = bf2f(x0[H_DIM + c]);
        const float xn0 = bf2f(x0[2 * H_DIM + c]);
        const float xr1 = bf2f(x1[c]);
        const float xz1 = bf2f(x1[H_DIM + c]);
        const float xn1 = bf2f(x1[2 * H_DIM + c]);

        const float r0 = sigmoidf(xr0 + ar0 + bh_r);
        const float z0 = sigmoidf(xz0 + az0 + bh_z);
        const float n0 = tanhf(xn0 + r0 * (an0 + bh_n));
        const float hprev0 = h[0][c];
        const float hn0 = (1.0f - z0) * n0 + z0 * hprev0;

        const float r1 = sigmoidf(xr1 + ar1 + bh_r);
        const float z1 = sigmoidf(xz1 + az1 + bh_z);
        const float n1 = tanhf(xn1 + r1 * (an1 + bh_n));
        const float hprev1 = h[1][c];
        const float hn1 = (1.0f - z1) * n1 + z1 * hprev1;

        __syncthreads();   // all k-loop reads of h done before overwrite
        h[0][c] = hn0;
        h[1][c] = hn1;

        out_seq[obase0 + (size_t)t * H_DIM + c] = hn0;
        out_seq[obase1 + (size_t)t * H_DIM + c] = hn1;
        __syncthreads();   // h update visible before next step's k-loop
    }

    out_last[(size_t)b0 * H_DIM + c] = h[0][c];
    out_last[(size_t)(b0 + 1) * H_DIM + c] = h[1][c];
}

extern "C" void kernel_launch(void* const* d_in, const int* in_sizes, int n_in,
                              void* d_out, int out_size, void* d_ws, size_t ws_size,
                              hipStream_t stream) {
    const float* inputs = (const float*)d_in[0];
    const float* W_in   = (const float*)d_in[1];
    const float* W_h    = (const float*)d_in[2];
    const float* bias   = (const float*)d_in[3];

    float* out_seq  = (float*)d_out;
    float* out_last = (float*)d_out + (size_t)B_DIM * S_DIM * H_DIM;

    ushort* xproj = (ushort*)d_ws;   // bf16 [131072][1536]

    // Phase 1: x_proj GEMM  (M=131072, N=1536, K=256)
    dim3 g1(B_DIM * S_DIM / BM, G_DIM / BN);
    xproj_gemm<<<g1, 256, 0, stream>>>(inputs, W_in, bias, xproj);

    // Phase 2: sequential scan, 64 blocks x 2 batch rows
    gru_scan<<<B_DIM / 2, H_DIM, 0, stream>>>(W_h, bias, xproj, out_seq, out_last);
}

// Round 2
// 17000.969 us; speedup vs baseline: 1.8387x; 1.8387x over previous
//
#include <hip/hip_runtime.h>
#include <hip/hip_bf16.h>

// GRU forward. B=128, S=1024, I=256, H=512.
// d_in: inputs f32 [128][1024][256], W_in f32 [256][1536], W_h f32 [512][1536],
//       bias f32 [3072] (b_in | b_h)
// d_out: hidden_sequence f32 [128][1024][512] then h_last f32 [128][512]
//
// Phase 1: x_proj = inputs@W_in + b_in, fp32 GEMM, stored bf16 in d_ws with a
//          per-scan-block sliced layout X[t][g][b][48].
// Phase 2: persistent 32-block scan. Block g owns h-cols [g*16, g*16+16):
//          W_h slice (48 cols) bf16 in LDS forever; per step MFMA
//          h[128][512]_bf16 @ Wh_slice -> [128][48], fp32 epilogue, global
//          h double-buffer (bf16) + per-step device-scope flag barrier.
//
// d_ws layout: [hA 128K][hB 128K][flags 128B pad to 512][X 402,653,184 B]

#define B_DIM 128
#define S_DIM 1024
#define I_DIM 256
#define H_DIM 512
#define G_DIM 1536
#define NBLK 32
#define SLICE 16
#define SL3 48

typedef __bf16 bf16x8 __attribute__((ext_vector_type(8)));
typedef float floatx4 __attribute__((ext_vector_type(4)));

static __device__ __forceinline__ float bf2f(unsigned short u) {
    union { unsigned int i; float f; } v;
    v.i = ((unsigned int)u) << 16;
    return v.f;
}

static __device__ __forceinline__ unsigned short f2bf(float f) {
    union { float f; unsigned int i; } v;
    v.f = f;
    unsigned int lsb = (v.i >> 16) & 1;
    v.i += 0x7fffu + lsb;
    return (unsigned short)(v.i >> 16);
}

static __device__ __forceinline__ float sigmoidf_fast(float x) {
    return 1.0f / (1.0f + __expf(-x));   // x<<0: exp->inf -> 0 (graceful)
}
static __device__ __forceinline__ float tanhf_fast(float x) {
    // 1 - 2/(e^{2x}+1); overflow-safe: e^inf -> inf -> 2/inf=0 -> 1
    return 1.0f - 2.0f / (__expf(2.0f * x) + 1.0f);
}

// ---------------------------------------------------------------------------
// Phase 1: x_proj GEMM (M=131072, K=256, N=1536), fp32, bf16 sliced output.
// ---------------------------------------------------------------------------
#define BM 64
#define BN 64
#define BK 16

__global__ __launch_bounds__(256) void xproj_gemm(
    const float* __restrict__ A,      // [131072][256]
    const float* __restrict__ W,      // [256][1536]
    const float* __restrict__ bias,   // b_in at offset 0
    unsigned short* __restrict__ X)   // sliced layout [t][32][128][48]
{
    __shared__ float As[BK][BM + 1];
    __shared__ float Bs[BK][BN];

    const int tid = threadIdx.x;
    const int tx = tid & 15;
    const int ty = tid >> 4;
    const long m0 = (long)blockIdx.x * BM;
    const int n0 = blockIdx.y * BN;

    const int arow = tid >> 2;
    const int akc = (tid & 3) * 4;
    const int bkr = tid >> 4;
    const int bnc = (tid & 15) * 4;

    float acc[4][4] = {};

    for (int k0 = 0; k0 < I_DIM; k0 += BK) {
        float4 av = *(const float4*)(A + (m0 + arow) * I_DIM + k0 + akc);
        As[akc + 0][arow] = av.x;
        As[akc + 1][arow] = av.y;
        As[akc + 2][arow] = av.z;
        As[akc + 3][arow] = av.w;
        float4 bv = *(const float4*)(W + (long)(k0 + bkr) * G_DIM + n0 + bnc);
        *(float4*)&Bs[bkr][bnc] = bv;
        __syncthreads();
#pragma unroll
        for (int k = 0; k < BK; ++k) {
            float a0 = As[k][ty * 4 + 0];
            float a1 = As[k][ty * 4 + 1];
            float a2 = As[k][ty * 4 + 2];
            float a3 = As[k][ty * 4 + 3];
            float4 b = *(const float4*)&Bs[k][tx * 4];
            acc[0][0] += a0 * b.x; acc[0][1] += a0 * b.y; acc[0][2] += a0 * b.z; acc[0][3] += a0 * b.w;
            acc[1][0] += a1 * b.x; acc[1][1] += a1 * b.y; acc[1][2] += a1 * b.z; acc[1][3] += a1 * b.w;
            acc[2][0] += a2 * b.x; acc[2][1] += a2 * b.y; acc[2][2] += a2 * b.z; acc[2][3] += a2 * b.w;
            acc[3][0] += a3 * b.x; acc[3][1] += a3 * b.y; acc[3][2] += a3 * b.z; acc[3][3] += a3 * b.w;
        }
        __syncthreads();
    }

    const int n = n0 + tx * 4;        // global gate column of acc[.][0]
    const int q = n >> 9;             // gate 0/1/2
    const int hc = n & 511;           // h-column
    const int g = hc >> 4;            // scan block slice
    const int c = hc & 15;            // col within slice
    const float b0v = bias[n + 0];
    const float b1v = bias[n + 1];
    const float b2v = bias[n + 2];
    const float b3v = bias[n + 3];
#pragma unroll
    for (int i = 0; i < 4; ++i) {
        const long m = m0 + ty * 4 + i;
        const int b = (int)(m >> 10);
        const int t = (int)(m & 1023);
        ushort4 o;
        o.x = f2bf(acc[i][0] + b0v);
        o.y = f2bf(acc[i][1] + b1v);
        o.z = f2bf(acc[i][2] + b2v);
        o.w = f2bf(acc[i][3] + b3v);
        size_t addr = (((size_t)t * NBLK + g) * B_DIM + b) * SL3 + q * SLICE + c;
        *(ushort4*)(X + addr) = o;
    }
}

// ---------------------------------------------------------------------------
// Phase 2: persistent MFMA scan. 32 blocks x 256 threads (4 waves).
// ---------------------------------------------------------------------------
__global__ __launch_bounds__(256) void gru_scan_mfma(
    const float* __restrict__ Wh,       // [512][1536]
    const float* __restrict__ bias,     // b_h at +1536
    const unsigned short* __restrict__ X, // [t][32][128][48] bf16
    unsigned short* __restrict__ hA,    // [128][512] bf16 (zeroed)
    unsigned short* __restrict__ hB,    // [128][512] bf16
    int* __restrict__ flags,            // [32] (zeroed)
    float* __restrict__ out_seq,        // [128][1024][512]
    float* __restrict__ out_last)       // [128][512]
{
    __shared__ __align__(16) unsigned short WtS[3][SLICE][520]; // [gate][col][k] pad 520
    __shared__ float hprevS[B_DIM][SLICE + 1];                  // fp32 carry, own slice

    const int tid  = threadIdx.x;
    const int g    = blockIdx.x;
    const int lane = tid & 63;
    const int wav  = tid >> 6;        // 0..3
    const int c    = lane & 15;       // N-col within slice / M-row within tile
    const int quad = lane >> 4;       // 0..3

    // ---- one-time: W_h slice -> LDS (bf16, transposed [gate][col][k]) ----
    for (int idx = tid; idx < 3 * SLICE * H_DIM; idx += 256) {
        int q   = idx >> 13;          // / 8192
        int rem = idx & 8191;
        int cc  = rem >> 9;           // / 512
        int k   = rem & 511;
        float w = Wh[(size_t)k * G_DIM + q * H_DIM + g * SLICE + cc];
        WtS[q][cc][k] = f2bf(w);
    }
    for (int idx = tid; idx < B_DIM * (SLICE + 1); idx += 256)
        ((float*)hprevS)[idx] = 0.0f;
    __syncthreads();

    const float bhr = bias[G_DIM + 0 * H_DIM + g * SLICE + c];
    const float bhz = bias[G_DIM + 1 * H_DIM + g * SLICE + c];
    const float bhn = bias[G_DIM + 2 * H_DIM + g * SLICE + c];

    const int mt0 = wav * 2;          // this wave's first M-tile (of 8)
    const int kc  = quad << 3;        // k-chunk offset within a K=32 step

    for (int t = 0; t < S_DIM; ++t) {
        const unsigned short* __restrict__ h_read  = (t & 1) ? hB : hA;
        unsigned short* __restrict__       h_write = (t & 1) ? hA : hB;

        floatx4 aR0 = {0.f,0.f,0.f,0.f}, aZ0 = aR0, aN0 = aR0;
        floatx4 aR1 = aR0, aZ1 = aR0, aN1 = aR0;

        const unsigned short* a0p = h_read + (size_t)(mt0 * 16 + c) * H_DIM + kc;
        const unsigned short* a1p = h_read + (size_t)((mt0 + 1) * 16 + c) * H_DIM + kc;

#pragma unroll 4
        for (int k0 = 0; k0 < H_DIM; k0 += 32) {
            bf16x8 bR = *(const bf16x8*)&WtS[0][c][k0 + kc];
            bf16x8 bZ = *(const bf16x8*)&WtS[1][c][k0 + kc];
            bf16x8 bN = *(const bf16x8*)&WtS[2][c][k0 + kc];
            bf16x8 a0 = *(const bf16x8*)(a0p + k0);
            bf16x8 a1 = *(const bf16x8*)(a1p + k0);
            aR0 = __builtin_amdgcn_mfma_f32_16x16x32_bf16(a0, bR, aR0, 0, 0, 0);
            aZ0 = __builtin_amdgcn_mfma_f32_16x16x32_bf16(a0, bZ, aZ0, 0, 0, 0);
            aN0 = __builtin_amdgcn_mfma_f32_16x16x32_bf16(a0, bN, aN0, 0, 0, 0);
            aR1 = __builtin_amdgcn_mfma_f32_16x16x32_bf16(a1, bR, aR1, 0, 0, 0);
            aZ1 = __builtin_amdgcn_mfma_f32_16x16x32_bf16(a1, bZ, aZ1, 0, 0, 0);
            aN1 = __builtin_amdgcn_mfma_f32_16x16x32_bf16(a1, bN, aN1, 0, 0, 0);
        }

        // ---- epilogue: fp32 gate math, write h_next + outputs ----
        const unsigned short* xp = X + ((size_t)t * NBLK + g) * (B_DIM * SL3);
#pragma unroll
        for (int mi = 0; mi < 2; ++mi) {
            const floatx4 aR = mi ? aR1 : aR0;
            const floatx4 aZ = mi ? aZ1 : aZ0;
            const floatx4 aN = mi ? aN1 : aN0;
#pragma unroll
            for (int r = 0; r < 4; ++r) {
                const int row = (mt0 + mi) * 16 + quad * 4 + r;   // batch row
                const float xr = bf2f(xp[row * SL3 + 0 * SLICE + c]);
                const float xz = bf2f(xp[row * SL3 + 1 * SLICE + c]);
                const float xn = bf2f(xp[row * SL3 + 2 * SLICE + c]);
                const float hp = hprevS[row][c];
                const float rr = sigmoidf_fast(xr + aR[r] + bhr);
                const float zz = sigmoidf_fast(xz + aZ[r] + bhz);
                const float nn = tanhf_fast(xn + rr * (aN[r] + bhn));
                const float hn = (1.0f - zz) * nn + zz * hp;
                hprevS[row][c] = hn;
                h_write[(size_t)row * H_DIM + g * SLICE + c] = f2bf(hn);
                out_seq[(size_t)row * (S_DIM * H_DIM) + (size_t)t * H_DIM + g * SLICE + c] = hn;
                if (t == S_DIM - 1)
                    out_last[(size_t)row * H_DIM + g * SLICE + c] = hn;
            }
        }

        // ---- device-scope barrier (skip after last step) ----
        if (t != S_DIM - 1) {
            __threadfence();
            __syncthreads();
            if (tid == 0)
                __hip_atomic_store(&flags[g], t + 1, __ATOMIC_RELEASE, __HIP_MEMORY_SCOPE_AGENT);
            if (tid < 64) {
                int ok;
                do {
                    int v = (lane < NBLK)
                        ? __hip_atomic_load(&flags[lane], __ATOMIC_RELAXED, __HIP_MEMORY_SCOPE_AGENT)
                        : (t + 1);
                    ok = __all(v >= t + 1);
                } while (!ok);
            }
            __threadfence();
            __syncthreads();
        }
    }
}

extern "C" void kernel_launch(void* const* d_in, const int* in_sizes, int n_in,
                              void* d_out, int out_size, void* d_ws, size_t ws_size,
                              hipStream_t stream) {
    const float* inputs = (const float*)d_in[0];
    const float* W_in   = (const float*)d_in[1];
    const float* W_h    = (const float*)d_in[2];
    const float* bias   = (const float*)d_in[3];

    float* out_seq  = (float*)d_out;
    float* out_last = (float*)d_out + (size_t)B_DIM * S_DIM * H_DIM;

    char* ws = (char*)d_ws;
    unsigned short* hA    = (unsigned short*)ws;                 // 131072 B
    unsigned short* hB    = (unsigned short*)(ws + 131072);      // 131072 B
    int*            flags = (int*)(ws + 262144);                 // 128 B
    unsigned short* X     = (unsigned short*)(ws + 262656);      // 402,653,184 B

    hipMemsetAsync(hA, 0, 131072, stream);
    hipMemsetAsync(flags, 0, 128, stream);

    dim3 g1(B_DIM * S_DIM / BM, G_DIM / BN);
    xproj_gemm<<<g1, 256, 0, stream>>>(inputs, W_in, bias, X);

    gru_scan_mfma<<<NBLK, 256, 0, stream>>>(W_h, bias, X, hA, hB, flags,
                                            out_seq, out_last);
}